// Round 2
// baseline (13784.561 us; speedup 1.0000x reference)
//
#include <hip/hip_runtime.h>
#include <stdint.h>
#include <math.h>

// ======================= config =======================
#define PARTITIONABLE 1   // jax_threefry_partitionable=True semantics (confirmed by round-1 correlation)

#define NS 8192
#define NSTEPS 200
#define DXc 8
#define DUc 4
#define DYc 8
#define DBc 128

typedef unsigned int u32;
typedef unsigned short u16;

// ws float-offset layout
#define WS_L0 0
#define WS_LE 64
#define WS_CONST 128   // [0]=c_ll, [1]=sum log diag Lerr, [2]=0.5*dx*log 2pi
#define WS_KEYS 144    // u32: 0,1=key_cur 2,3=key_init 4,5=k_anc 6,7=k_ref 8,9=k_state
#define WS_IDXALL 160  // int[200]
#define WS_AUX   1024                    // NS*8
#define WS_LLAUX (WS_AUX + NS*DXc)       // NS
#define WS_S1    (WS_LLAUX + NS)         // NS
#define WS_S2    (WS_S1 + NS)            // NS
#define WS_LOGW  (WS_S2 + NS)            // NS
#define WS_ANC_F (WS_LOGW + NS)          // u16[199*NS] -> 815104 floats
#define WS_TRACE (WS_ANC_F + (NSTEPS-1)*NS/2)  // float[200*NS*8] = 52.4 MB

// ======================= threefry2x32-20 =======================
__device__ __forceinline__ u32 rotl32(u32 v, int r){ return (v<<r)|(v>>(32-r)); }

__device__ __forceinline__ void tf2x32(u32 k0,u32 k1,u32 c0,u32 c1,u32&o0,u32&o1){
  u32 ks2 = k0^k1^0x1BD11BDAu;
  u32 x0=c0+k0, x1=c1+k1;
#define TFR(R) { x0+=x1; x1=rotl32(x1,(R)); x1^=x0; }
  TFR(13) TFR(15) TFR(26) TFR(6)
  x0+=k1;  x1+=ks2+1u;
  TFR(17) TFR(29) TFR(16) TFR(24)
  x0+=ks2; x1+=k0+2u;
  TFR(13) TFR(15) TFR(26) TFR(6)
  x0+=k0;  x1+=k1+3u;
  TFR(17) TFR(29) TFR(16) TFR(24)
  x0+=k1;  x1+=ks2+4u;
  TFR(13) TFR(15) TFR(26) TFR(6)
  x0+=ks2; x1+=k0+5u;
#undef TFR
  o0=x0; o1=x1;
}

__device__ __forceinline__ u32 jax_bits_elem(u32 k0,u32 k1,u32 i,u32 total){
#if PARTITIONABLE
  (void)total;
  u32 a,b; tf2x32(k0,k1,0u,i,a,b); return a^b;
#else
  if (total==1u){ u32 a,b; tf2x32(k0,k1,0u,0u,a,b); return a; }
  u32 half = total>>1; u32 a,b;
  if (i<half){ tf2x32(k0,k1,i,i+half,a,b); return a; }
  tf2x32(k0,k1,i-half,i,a,b); return b;
#endif
}

__device__ __forceinline__ void jax_split2(u32 k0,u32 k1,u32&c00,u32&c01,u32&c10,u32&c11){
#if PARTITIONABLE
  tf2x32(k0,k1,0u,0u,c00,c01);
  tf2x32(k0,k1,0u,1u,c10,c11);
#else
  u32 a0,a1,b0,b1;
  tf2x32(k0,k1,0u,2u,a0,a1);
  tf2x32(k0,k1,1u,3u,b0,b1);
  c00=a0; c01=b0; c10=a1; c11=b1;
#endif
}

__device__ __forceinline__ float bits_to_f01(u32 bits){
  return __uint_as_float((bits>>9)|0x3f800000u) - 1.0f;
}

// Kahan-trick log1p (matches high-accuracy libm/Eigen behavior to ~1 ulp)
__device__ __forceinline__ float log1pf_acc(float a){
#pragma clang fp contract(off)
  float u = 1.0f + a;
  if (u == 1.0f) return a;
  float l = logf(u);
  return l * (a / (u - 1.0f));
}

// XLA ErfInv32 (Giles)
__device__ __forceinline__ float erfinv_xla(float x){
#pragma clang fp contract(off)
  float a = -(x*x);
  float w = -log1pf_acc(a);
  float p;
  if (w < 5.0f){
    w = w - 2.5f;
    p = 2.81022636e-08f;
    p = 3.43273939e-07f + p*w;
    p = -3.5233877e-06f + p*w;
    p = -4.39150654e-06f + p*w;
    p = 0.00021858087f  + p*w;
    p = -0.00125372503f + p*w;
    p = -0.00417768164f + p*w;
    p = 0.246640727f    + p*w;
    p = 1.50140941f     + p*w;
  } else {
    w = sqrtf(w) - 3.0f;
    p = -0.000200214257f;
    p = 0.000100950558f + p*w;
    p = 0.00134934322f  + p*w;
    p = -0.00367342844f + p*w;
    p = 0.00573950773f  + p*w;
    p = -0.0076224613f  + p*w;
    p = 0.00943887047f  + p*w;
    p = 1.00167406f     + p*w;
    p = 2.83297682f     + p*w;
  }
  return p*x;
}

// jax.random.normal element. (maxval-minval) rounds to exactly 2.0f in f32.
// sqrt(2) is an f32 constant (0x3FB504F3) — reference multiplies in f32.
__device__ __forceinline__ float jax_normal_elem(u32 k0,u32 k1,u32 i,u32 total){
#pragma clang fp contract(off)
  float f = bits_to_f01(jax_bits_elem(k0,k1,i,total));
  float u = f*2.0f + (-0.99999994039535522f);
  u = fmaxf(-0.99999994039535522f, u);
  return 1.41421356237309515f * erfinv_xla(u);
}

__device__ __forceinline__ float jax_uniform01_scalar(u32 k0,u32 k1){
  return bits_to_f01(jax_bits_elem(k0,k1,0u,1u));
}

// ======================= kernels =======================

__global__ void k_pre(const float* __restrict__ icov, const float* __restrict__ ecov,
                      const int* __restrict__ seedp, float* wsf){
  if (threadIdx.x!=0 || blockIdx.x!=0) return;
  float* L0 = wsf+WS_L0; float* LE = wsf+WS_LE; float* CST = wsf+WS_CONST;
  u32* KEYS = (u32*)(wsf+WS_KEYS);
  for (int rep=0; rep<2; rep++){
    const float* A = rep? ecov : icov;
    float* L = rep? LE : L0;
    for (int c=0;c<8;c++){
      for (int r=c;r<8;r++){
        float s=A[r*8+c];
        for(int k=0;k<c;k++) s -= L[r*8+k]*L[c*8+k];
        L[r*8+c] = (r==c)? sqrtf(s) : s/L[c*8+c];
      }
      for (int cc=c+1; cc<8; cc++) L[c*8+cc]=0.0f;
    }
  }
  float c2 = (float)(2.0*M_PI*0.1*0.1);
  CST[0] = 4.0f*logf(c2);
  float hc1=0.0f; for(int d=0;d<8;d++) hc1 += logf(LE[d*8+d]);
  CST[1]=hc1;
  CST[2]=4.0f*logf((float)(2.0*M_PI));
  int seed = seedp[0];
  u32 k0=0u, k1=(u32)seed;
  u32 c00,c01,c10,c11;
  jax_split2(k0,k1,c00,c01,c10,c11);      // key_cur, key_init
  KEYS[0]=c00; KEYS[1]=c01; KEYS[2]=c10; KEYS[3]=c11;
}

__global__ void k_init(const float* __restrict__ mean, const float* __restrict__ refst, float* wsf){
  int i = blockIdx.x*blockDim.x + threadIdx.x;
  if (i>=NS) return;
  float* L0=wsf+WS_L0; float* LW=wsf+WS_LOGW;
  float* TR0=wsf+WS_TRACE;               // trace row 0
  u32* KEYS=(u32*)(wsf+WS_KEYS);
  u32 k0=KEYS[2], k1=KEYS[3];
  float st[8];
  if (i==NS-1){
    for(int d=0;d<8;d++) st[d]=refst[d];
  } else {
    float eps[8];
    for(int d=0;d<8;d++) eps[d]=jax_normal_elem(k0,k1,(u32)(i*8+d),(u32)(NS*8));
    for(int d=0;d<8;d++){
      float m=0.0f;
      for(int k=0;k<=d;k++) m += eps[k]*L0[d*8+k];
      st[d]=mean[d]+m;
    }
  }
  for(int d=0;d<8;d++) TR0[i*8+d]=st[d];
  LW[i]=0.0f;
}

__global__ void k_a(const float* __restrict__ obs, const float* __restrict__ inp,
                    const float* __restrict__ refst, const float* __restrict__ coeff,
                    const float* __restrict__ Omega, const float* __restrict__ phase,
                    const float* __restrict__ Cm, float* wsf, int t){
  int i = blockIdx.x*blockDim.x + threadIdx.x;
  float* AX=wsf+WS_AUX; float* LL=wsf+WS_LLAUX;
  float* S1=wsf+WS_S1; float* S2=wsf+WS_S2; float* LW=wsf+WS_LOGW;
  float* LE=wsf+WS_LE; float* CST=wsf+WS_CONST;
  const float* TRprev = wsf+WS_TRACE + (size_t)(t-1)*NS*DXc;
  u32* KEYS=(u32*)(wsf+WS_KEYS);

  if (i==0){
    // advance key chain for this step (matches scan_step's split sequence)
    u32 n0,n1,s0,s1v;
    jax_split2(KEYS[0],KEYS[1],n0,n1,s0,s1v);   // key, key_step
    KEYS[0]=n0; KEYS[1]=n1;
    u32 t0,t1,a0,a1;
    jax_split2(s0,s1v,t0,t1,a0,a1);             // key_step, k_anc
    KEYS[4]=a0; KEYS[5]=a1;
    u32 u0,u1,r0,r1;
    jax_split2(t0,t1,u0,u1,r0,r1);              // key_step, k_ref
    KEYS[6]=r0; KEYS[7]=r1;
    u32 v0,v1,w0,w1;
    jax_split2(u0,u1,v0,v1,w0,w1);              // _, k_state
    KEYS[8]=w0; KEYS[9]=w1;
  }
  if (i>=NS) return;

  float z[12];
  for(int d=0;d<8;d++) z[d]=TRprev[i*8+d];
  for(int k=0;k<4;k++) z[8+k]=inp[t*4+k];
  float ax[8]={0,0,0,0,0,0,0,0};
  for(int j=0;j<DBc;j++){
    float dot=0.0f;
    #pragma unroll
    for(int k=0;k<12;k++) dot += z[k]*Omega[j*12+k];
    float b = cosf(dot + phase[j]);
    #pragma unroll
    for(int d=0;d<8;d++) ax[d] += b*coeff[d*DBc+j];
  }
  for(int d=0;d<8;d++) AX[i*8+d]=ax[d];

  const float SSQ = (float)(0.1*0.1);
  float S=0.0f;
  for(int d=0;d<8;d++){
    float m=0.0f;
    #pragma unroll
    for(int k=0;k<8;k++) m += ax[k]*Cm[d*8+k];
    float r = obs[t*8+d]-m;
    S += r*r;
  }
  float ll = (-0.5f*S)/SSQ - CST[0];

  float sol[8]; float q=0.0f;
  for(int d=0;d<8;d++){
    float s = refst[t*8+d]-ax[d];
    for(int k=0;k<d;k++) s -= LE[d*8+k]*sol[k];
    sol[d]=s/LE[d*8+d];
    q += sol[d]*sol[d];
  }
  float h = (-0.5f*q - CST[1]) - CST[2];
  float lw = LW[i];
  float s1 = ll + lw;
  LL[i]=ll; S1[i]=s1; S2[i]=s1+h;
}

__global__ __launch_bounds__(1024) void k_b(float* wsf, int t){
  __shared__ float sh[NS];
  __shared__ float r1[1024];
  __shared__ float r2[1024];
  __shared__ float scal[1];
  int tid=threadIdx.x; int base=tid*8;
  float* S1=wsf+WS_S1; float* S2=wsf+WS_S2;
  u32* KEYS=(u32*)(wsf+WS_KEYS);
  u16* ANC=(u16*)(wsf+WS_ANC_F) + (size_t)(t-1)*NS;

  for(int pass=0; pass<2; pass++){
    const float* Sv = pass? S2 : S1;
    float v[8]; float m=-INFINITY;
    for(int k=0;k<8;k++){ v[k]=Sv[base+k]; m=fmaxf(m,v[k]); }
    r1[tid]=m; __syncthreads();
    for(int off=512; off>0; off>>=1){ if(tid<off) r1[tid]=fmaxf(r1[tid],r1[tid+off]); __syncthreads(); }
    float M=r1[0]; __syncthreads();
    float e[8]; float cs=0.0f;
    for(int k=0;k<8;k++){ e[k]=expf(v[k]-M); cs+=e[k]; }
    r1[tid]=cs; __syncthreads();
    for(int off=512; off>0; off>>=1){ if(tid<off) r1[tid]+=r1[tid+off]; __syncthreads(); }
    float T=r1[0]; __syncthreads();
    float w[8]; float wcs=0.0f;
    for(int k=0;k<8;k++){ w[k]=e[k]/T; wcs+=w[k]; }
    float* src=r1; float* dst=r2;
    src[tid]=wcs; __syncthreads();
    for(int off=1; off<1024; off<<=1){
      float x=src[tid]; if(tid>=off) x+=src[tid-off];
      dst[tid]=x; __syncthreads();
      float* tmp=src; src=dst; dst=tmp;
    }
    float excl = (tid==0)?0.0f:src[tid-1];
    __syncthreads();
    float run=excl;
    for(int k=0;k<8;k++){ run+=w[k]; sh[base+k]=run; }
    __syncthreads();
    if (pass==0){
      if(tid==0) scal[0]=jax_uniform01_scalar(KEYS[4],KEYS[5]);
      __syncthreads();
      float u=scal[0];
      for(int k=0;k<8;k++){
        int idx=base+k;
        float pos = ((float)idx + u) * (1.0f/8192.0f);
        int lo=0, hi=NS;
        while(lo<hi){ int mid=(lo+hi)>>1; if (sh[mid]<pos) lo=mid+1; else hi=mid; }
        if (lo>NS-1) lo=NS-1;
        ANC[idx]=(u16)lo;
      }
    } else {
      if(tid==0){
        float u=jax_uniform01_scalar(KEYS[6],KEYS[7]);
        int lo=0, hi=NS;
        while(lo<hi){ int mid=(lo+hi)>>1; if (sh[mid]<u) lo=mid+1; else hi=mid; }
        if (lo>NS-1) lo=NS-1;
        ANC[NS-1]=(u16)lo;   // a_idx.at[-1].set(ref_idx)
      }
    }
    __syncthreads();
  }
}

__global__ void k_c(const float* __restrict__ obs, const float* __restrict__ refst,
                    const float* __restrict__ Cm, float* wsf, int t){
  int i = blockIdx.x*blockDim.x + threadIdx.x;
  if (i>=NS) return;
  float* AX=wsf+WS_AUX; float* LL=wsf+WS_LLAUX;
  float* LW=wsf+WS_LOGW; float* LE=wsf+WS_LE; float* CST=wsf+WS_CONST;
  float* TRt = wsf+WS_TRACE + (size_t)t*NS*DXc;
  u32* KEYS=(u32*)(wsf+WS_KEYS);
  const u16* ANC=(const u16*)(wsf+WS_ANC_F) + (size_t)(t-1)*NS;
  u32 k0=KEYS[8], k1=KEYS[9];
  float st[8];
  if (i==NS-1){
    for(int d=0;d<8;d++) st[d]=refst[t*8+d];
  } else {
    float eps[8];
    for(int d=0;d<8;d++) eps[d]=jax_normal_elem(k0,k1,(u32)(i*8+d),(u32)(NS*8));
    for(int d=0;d<8;d++){
      float m=0.0f;
      for(int k=0;k<=d;k++) m += eps[k]*LE[d*8+k];
      st[d]=AX[i*8+d]+m;
    }
  }
  const float SSQ=(float)(0.1*0.1);
  float S=0.0f;
  for(int d=0;d<8;d++){
    float m=0.0f;
    #pragma unroll
    for(int k=0;k<8;k++) m += st[k]*Cm[d*8+k];
    float r=obs[t*8+d]-m; S+=r*r;
  }
  float ll=(-0.5f*S)/SSQ - CST[0];
  int a=(int)ANC[i];
  LW[i]=ll-LL[a];
  for(int d=0;d<8;d++) TRt[i*8+d]=st[d];
}

__global__ __launch_bounds__(1024) void k_f(float* wsf){
  __shared__ float sh[NS];
  __shared__ float r1[1024];
  __shared__ float r2[1024];
  int tid=threadIdx.x; int base=tid*8;
  float* LW=wsf+WS_LOGW;
  u32* KEYS=(u32*)(wsf+WS_KEYS);
  int* IDX=(int*)(wsf+WS_IDXALL);
  const u16* ANC=(const u16*)(wsf+WS_ANC_F);
  float v[8]; float m=-INFINITY;
  for(int k=0;k<8;k++){ v[k]=LW[base+k]; m=fmaxf(m,v[k]); }
  r1[tid]=m; __syncthreads();
  for(int off=512;off>0;off>>=1){ if(tid<off) r1[tid]=fmaxf(r1[tid],r1[tid+off]); __syncthreads(); }
  float M=r1[0]; __syncthreads();
  float e[8]; float cs=0.0f;
  for(int k=0;k<8;k++){ e[k]=expf(v[k]-M); cs+=e[k]; }
  r1[tid]=cs; __syncthreads();
  for(int off=512;off>0;off>>=1){ if(tid<off) r1[tid]+=r1[tid+off]; __syncthreads(); }
  float T=r1[0]; __syncthreads();
  float w[8]; float wcs=0.0f;
  for(int k=0;k<8;k++){ w[k]=e[k]/T; wcs+=w[k]; }
  float* src=r1; float* dst=r2;
  src[tid]=wcs; __syncthreads();
  for(int off=1;off<1024;off<<=1){
    float x=src[tid]; if(tid>=off) x+=src[tid-off];
    dst[tid]=x; __syncthreads(); float* tmp=src; src=dst; dst=tmp;
  }
  float excl=(tid==0)?0.0f:src[tid-1];
  __syncthreads();
  float run=excl;
  for(int k=0;k<8;k++){ run+=w[k]; sh[base+k]=run; }
  __syncthreads();
  if (tid==0){
    float u=jax_uniform01_scalar(KEYS[0],KEYS[1]);
    int lo=0,hi=NS;
    while(lo<hi){ int mid=(lo+hi)>>1; if(sh[mid]<u) lo=mid+1; else hi=mid; }
    if(lo>NS-1) lo=NS-1;
    int b=lo;
    IDX[NSTEPS-1]=b;
    for(int r=NSTEPS-2;r>=0;r--){ b=(int)ANC[(size_t)r*NS + b]; IDX[r]=b; }
  }
}

// gather: out[t][d] = TRACE[t][idx_all[t]][d]
__global__ void k_g(const float* __restrict__ wsf, float* __restrict__ out){
  int e = blockIdx.x*blockDim.x + threadIdx.x;
  if (e >= NSTEPS*DXc) return;
  int t = e >> 3, d = e & 7;
  const int* IDX = (const int*)(wsf+WS_IDXALL);
  int j = IDX[t];
  out[e] = wsf[WS_TRACE + ((size_t)t*NS + j)*DXc + d];
}

// ======================= launch =======================
extern "C" void kernel_launch(void* const* d_in, const int* in_sizes, int n_in,
                              void* d_out, int out_size, void* d_ws, size_t ws_size,
                              hipStream_t stream) {
  const float* obs  =(const float*)d_in[0];
  const float* inp  =(const float*)d_in[1];
  const float* mean =(const float*)d_in[2];
  const float* icov =(const float*)d_in[3];
  const float* coeff=(const float*)d_in[4];
  const float* ecov =(const float*)d_in[5];
  const float* refst=(const float*)d_in[6];
  const float* Om   =(const float*)d_in[7];
  const float* ph   =(const float*)d_in[8];
  const float* Cm   =(const float*)d_in[9];
  const int*   seedp=(const int*)d_in[10];
  float* wsf=(float*)d_ws;
  float* out=(float*)d_out;

  hipLaunchKernelGGL(k_pre, dim3(1), dim3(64), 0, stream, icov, ecov, seedp, wsf);
  hipLaunchKernelGGL(k_init, dim3(NS/256), dim3(256), 0, stream, mean, refst, wsf);
  for(int t=1;t<NSTEPS;t++){
    hipLaunchKernelGGL(k_a, dim3(NS/256), dim3(256), 0, stream, obs, inp, refst, coeff, Om, ph, Cm, wsf, t);
    hipLaunchKernelGGL(k_b, dim3(1), dim3(1024), 0, stream, wsf, t);
    hipLaunchKernelGGL(k_c, dim3(NS/256), dim3(256), 0, stream, obs, refst, Cm, wsf, t);
  }
  hipLaunchKernelGGL(k_f, dim3(1), dim3(1024), 0, stream, wsf);
  hipLaunchKernelGGL(k_g, dim3((NSTEPS*DXc+255)/256), dim3(256), 0, stream, wsf, out);
}